// Round 1
// baseline (174.295 us; speedup 1.0000x reference)
//
#include <hip/hip_runtime.h>
#include <math.h>

// RandomMicEQ: cascade of 3 biquads (EQ -> LP -> HP), stage outputs clamped
// to [-1,1], recursion history UNCLAMPED (matches jax ref).
//
// Overlap-save chunking: thread = one L-sample chunk, run from zero state
// W samples early. Dominant pole r=0.9702 (HP@300Hz): transient at W=192
// ~ 9e-4 (= 1.3e-4 measured at W=256 x r^-64), under 7.7e-3 threshold on
// top of the 1.95e-3 fp32-roundoff floor.
//
// R4: occupancy push. R3 counters showed latency-bound (Occ 15%, VALU 31%,
// HBM 26%; L3-warm dispatches same dur -> not BW-bound) with only 1.69
// waves/SIMD. L 128->64, W 256->192: waves 1728->3456 (3.4/SIMD), per-wave
// serial work 384->256 samples. LDS staging single-buffered (8.4 KB/block,
// was 16.9 KB) so LDS allows 19 blocks/CU and doesn't cap the new
// 13.5 blocks/CU average. Coalesced wave-cooperative flush kept from R3
// (WRITE_SIZE at 60 MB ideal).

struct BQ { float b0, b1, b2, a1, a2; };

#define L_CHUNK 64
#define W_WARM  192
#define PIECE   32
#define NPIECE  (L_CHUNK / PIECE)   // 2
#define NCH     64                  // chunks per block (= block size)
#define PITCH   33                  // dword pitch per chunk in LDS (pad +1)
#define PF      4                   // float4 prefetch depth

__global__ __launch_bounds__(64) void biquad3_kernel(
    const float* __restrict__ x, float* __restrict__ out,
    int T, int chunksPerRow, BQ F1, BQ F2, BQ F3)
{
    __shared__ float lds[NCH * PITCH];   // single-buffered piece staging, 8448 B

    const int lane   = threadIdx.x;
    const int row    = blockIdx.y;
    const int chunk0 = blockIdx.x * NCH;
    const int chunk  = chunk0 + lane;
    const bool alive = chunk < chunksPerRow;

    const float* xr = x   + (size_t)row * T;
    float*       yr = out + (size_t)row * T;

    const int t0 = chunk * L_CHUNK;
    int begin = t0 - W_WARM; if (begin < 0) begin = 0;
    int end   = t0 + L_CHUNK; if (end > T) end = T;
    if (!alive) { begin = 0; end = 0; }

    // direct-form I states for the 3 stages
    float x1=0.f,x2=0.f,y1=0.f,y2=0.f;
    float u1=0.f,u2=0.f,v1=0.f,v2=0.f;
    float p1=0.f,p2=0.f,q1=0.f,q2=0.f;

    // rotating float4 prefetch pipeline over [begin, end)
    float4 buf[PF];
    int tpre = begin;
#pragma unroll
    for (int j = 0; j < PF; ++j) {
        buf[j] = (tpre < end) ? *(const float4*)(xr + tpre)
                              : make_float4(0.f,0.f,0.f,0.f);
        tpre += 4;
    }
    auto nextvec = [&]() -> float4 {
        float4 c = buf[0];
        buf[0] = buf[1]; buf[1] = buf[2]; buf[2] = buf[3];
        if (tpre < end) buf[3] = *(const float4*)(xr + tpre);
        tpre += 4;
        return c;
    };

    auto step = [&](float xt) -> float {
        float f = F1.b0*xt + F1.b1*x1 + F1.b2*x2;
        float y = (f - F1.a2*y2) - F1.a1*y1;
        x2 = x1; x1 = xt; y2 = y1; y1 = y;
        float u = fminf(fmaxf(y, -1.f), 1.f);

        float g = F2.b0*u + F2.b1*u1 + F2.b2*u2;
        float v = (g - F2.a2*v2) - F2.a1*v1;
        u2 = u1; u1 = u; v2 = v1; v1 = v;
        float pp = fminf(fmaxf(v, -1.f), 1.f);

        float h = F3.b0*pp + F3.b1*p1 + F3.b2*p2;
        float q = (h - F3.a2*q2) - F3.a1*q1;
        p2 = p1; p1 = pp; q2 = q1; q1 = q;
        return fminf(fmaxf(q, -1.f), 1.f);
    };

    // ---- warm-up: run cascade, discard output ----
    if (alive) {
        for (int t = begin; t < t0; t += 4) {
            float4 c = nextvec();
            step(c.x); step(c.y); step(c.z); step(c.w);
        }
    }

    // contiguous output span of this block (64 consecutive chunks)
    const int spanBase = chunk0 * L_CHUNK;
    int spanEnd = spanBase + NCH * L_CHUNK;
    if (spanEnd > T) spanEnd = T;

    // ---- output: compute 32-sample pieces into LDS, flush coalesced ----
    for (int p = 0; p < NPIECE; ++p) {
        if (p) __syncthreads();   // WAR: previous flush must be done (1-wave: cheap)
        if (alive) {
            float* myrow = lds + lane * PITCH;
#pragma unroll
            for (int s = 0; s < PIECE; s += 4) {
                float4 c = nextvec();
                myrow[s+0] = step(c.x);
                myrow[s+1] = step(c.y);
                myrow[s+2] = step(c.z);
                myrow[s+3] = step(c.w);
            }
        }
        __syncthreads();   // writes visible wave-wide (1-wave block: cheap)
        // flush: 64 chunks x 32 floats; per instruction 64 lanes cover
        // 8 x 128B contiguous aligned segments -> no partial-line RMW
#pragma unroll
        for (int i = lane * 4; i < NCH * PIECE; i += 64 * 4) {
            int c = i >> 5;           // / PIECE
            int j = i & (PIECE - 1);
            int g = spanBase + c * L_CHUNK + p * PIECE + j;
            if (g < spanEnd) {
                // scalar LDS reads (pitch 33 keeps banks 2-way = free)
                float4 v4 = make_float4(lds[c*PITCH + j],
                                        lds[c*PITCH + j + 1],
                                        lds[c*PITCH + j + 2],
                                        lds[c*PITCH + j + 3]);
                *(float4*)(yr + g) = v4;
            }
        }
    }
}

// ---- host-side coefficient computation (double, matching numpy refs) ----

static BQ norm_ba(double b0, double b1, double b2,
                  double a0, double a1, double a2) {
    BQ r;
    r.b0 = (float)(b0/a0); r.b1 = (float)(b1/a0); r.b2 = (float)(b2/a0);
    r.a1 = (float)(a1/a0); r.a2 = (float)(a2/a0);
    return r;
}

static BQ make_eq(double f0, double gain_db, double Q) {
    const double SR = 44100.0;
    double w0 = 2.0 * M_PI * f0 / SR;
    double alpha = sin(w0) / (2.0 * Q);
    double A = pow(10.0, gain_db / 40.0);
    return norm_ba(1.0 + alpha*A, -2.0*cos(w0), 1.0 - alpha*A,
                   1.0 + alpha/A, -2.0*cos(w0), 1.0 - alpha/A);
}

static BQ make_lp(double cutoff, double Q) {
    const double SR = 44100.0;
    double w0 = 2.0 * M_PI * cutoff / SR;
    double alpha = sin(w0) / (2.0 * Q);
    double c = cos(w0);
    return norm_ba((1.0-c)/2.0, 1.0-c, (1.0-c)/2.0,
                   1.0+alpha, -2.0*c, 1.0-alpha);
}

static BQ make_hp(double cutoff, double Q) {
    const double SR = 44100.0;
    double w0 = 2.0 * M_PI * cutoff / SR;
    double alpha = sin(w0) / (2.0 * Q);
    double c = cos(w0);
    return norm_ba((1.0+c)/2.0, -(1.0+c), (1.0+c)/2.0,
                   1.0+alpha, -2.0*c, 1.0-alpha);
}

extern "C" void kernel_launch(void* const* d_in, const int* in_sizes, int n_in,
                              void* d_out, int out_size, void* d_ws, size_t ws_size,
                              hipStream_t stream) {
    const float* x = (const float*)d_in[0];
    float* out = (float*)d_out;

    const int T = 441000;
    int total = in_sizes[0];
    int B = total / T;                                  // 32

    int chunksPerRow = (T + L_CHUNK - 1) / L_CHUNK;     // 6891
    int wavesPerRow  = (chunksPerRow + NCH - 1) / NCH;  // 108

    BQ f1 = make_eq(1000.0, 6.0, 1.0);
    BQ f2 = make_lp(8000.0, 0.7071067811865476);
    BQ f3 = make_hp(300.0, 0.7071067811865476);

    dim3 grid(wavesPerRow, B);
    hipLaunchKernelGGL(biquad3_kernel, grid, dim3(64), 0, stream,
                       x, out, T, chunksPerRow, f1, f2, f3);
}

// Round 2
// 162.125 us; speedup vs baseline: 1.0751x; 1.0751x over previous
//
#include <hip/hip_runtime.h>
#include <math.h>

// RandomMicEQ: cascade of 3 biquads (EQ -> LP -> HP), stage outputs clamped
// to [-1,1], recursion history UNCLAMPED (matches jax ref).
//
// Overlap-save chunking: thread = one L-sample chunk, run from zero state
// W samples early. W=192: transient ~9e-4 under the 7.7e-3 threshold on top
// of the 1.95e-3 fp32-roundoff floor (absmax measured W-independent).
//
// R5: LDS input staging. R4 counters: FETCH 228MB = full 4x logical
// redundancy (L2 stopped absorbing overlap), VALUBusy 32% flat while
// occupancy doubled -> waves 93% stalled on strided L3/HBM reads
// (~680 cyc/sample wall vs ~50 issue demand). Fix: each block stages its
// UNIQUE 4288-float span once, coalesced (1KB/instr), into LDS with
// +1-dword-per-64 pad (lane-stride-64 reads become pitch-65 -> 2-way bank
// alias = free). Compute reads now hit LDS (~120cy, prefetchable) not
// L3/HBM (~600-900cy). Input zero-padded outside [0,T): zeros through a
// zero-state causal filter keep state zero == shorter warm-up, bit-identical,
// and all lanes run uniform control flow.
// LDS 25.9KB/block -> ~6 blocks/CU (19% occ): fewer waves, but un-stalled.

struct BQ { float b0, b1, b2, a1, a2; };

#define L_CHUNK 64
#define W_WARM  192
#define PIECE   32
#define NPIECE  (L_CHUNK / PIECE)            // 2
#define NCH     64                           // chunks per block (= block size)
#define PITCH   33                           // output staging pitch (pad +1)
#define SPAN    (NCH * L_CHUNK + W_WARM)     // 4288 dwords unique input span
#define SPAN_LDS (SPAN + SPAN / 64 + 8)      // padded: +1 dword per 64

__global__ __launch_bounds__(64) void biquad3_kernel(
    const float* __restrict__ x, float* __restrict__ out,
    int T, BQ F1, BQ F2, BQ F3)
{
    __shared__ float xin[SPAN_LDS];          // padded input span, 17.4 KB
    __shared__ float ost[NCH * PITCH];       // output piece staging, 8448 B

    const int lane   = threadIdx.x;
    const int row    = blockIdx.y;
    const int chunk0 = blockIdx.x * NCH;

    const float* xr = x   + (size_t)row * T;
    float*       yr = out + (size_t)row * T;

    // block's input span: [base, base + SPAN), may extend past [0,T)
    const int base = chunk0 * L_CHUNK - W_WARM;

    // ---- stage unique span, coalesced; zeros outside [0,T) ----
    for (int m = lane * 4; m < SPAN; m += 64 * 4) {
        int g = base + m;
        float4 v;
        if (g >= 0 && g + 4 <= T) {
            v = *(const float4*)(xr + g);
        } else {
            v.x = ((unsigned)(g+0) < (unsigned)T) ? xr[g+0] : 0.f;
            v.y = ((unsigned)(g+1) < (unsigned)T) ? xr[g+1] : 0.f;
            v.z = ((unsigned)(g+2) < (unsigned)T) ? xr[g+2] : 0.f;
            v.w = ((unsigned)(g+3) < (unsigned)T) ? xr[g+3] : 0.f;
        }
        int pm = m + (m >> 6);               // pad: +1 dword per 64
        xin[pm+0] = v.x; xin[pm+1] = v.y; xin[pm+2] = v.z; xin[pm+3] = v.w;
    }
    __syncthreads();

    // direct-form I states for the 3 stages
    float x1=0.f,x2=0.f,y1=0.f,y2=0.f;
    float u1=0.f,u2=0.f,v1=0.f,v2=0.f;
    float p1=0.f,p2=0.f,q1=0.f,q2=0.f;

    auto step = [&](float xt) -> float {
        float f = F1.b0*xt + F1.b1*x1 + F1.b2*x2;
        float y = (f - F1.a2*y2) - F1.a1*y1;
        x2 = x1; x1 = xt; y2 = y1; y1 = y;
        float u = fminf(fmaxf(y, -1.f), 1.f);

        float g = F2.b0*u + F2.b1*u1 + F2.b2*u2;
        float v = (g - F2.a2*v2) - F2.a1*v1;
        u2 = u1; u1 = u; v2 = v1; v1 = v;
        float pp = fminf(fmaxf(v, -1.f), 1.f);

        float h = F3.b0*pp + F3.b1*p1 + F3.b2*p2;
        float q = (h - F3.a2*q2) - F3.a1*q1;
        p2 = p1; p1 = pp; q2 = q1; q1 = q;
        return fminf(fmaxf(q, -1.f), 1.f);
    };

    const int mb = lane * L_CHUNK;           // lane's window base within span

    // ---- warm-up: run cascade on LDS data, discard output ----
#pragma unroll 2
    for (int s = 0; s < W_WARM; s += 4) {
        int m = mb + s;
        int pm = m + (m >> 6);               // quad never crosses a 64-block
        step(xin[pm+0]); step(xin[pm+1]); step(xin[pm+2]); step(xin[pm+3]);
    }

    // contiguous output span of this block (64 consecutive chunks)
    const int spanBase = chunk0 * L_CHUNK;
    int spanEnd = spanBase + NCH * L_CHUNK;
    if (spanEnd > T) spanEnd = T;

    // ---- output: compute 32-sample pieces into LDS, flush coalesced ----
    for (int p = 0; p < NPIECE; ++p) {
        if (p) __syncthreads();              // WAR vs previous flush (1-wave: cheap)
        float* myrow = ost + lane * PITCH;
#pragma unroll
        for (int s0 = 0; s0 < PIECE; s0 += 4) {
            int m = mb + W_WARM + p * PIECE + s0;
            int pm = m + (m >> 6);
            myrow[s0+0] = step(xin[pm+0]);
            myrow[s0+1] = step(xin[pm+1]);
            myrow[s0+2] = step(xin[pm+2]);
            myrow[s0+3] = step(xin[pm+3]);
        }
        __syncthreads();                     // piece writes visible
        // flush: 64 chunks x 32 floats; per instruction 64 lanes cover
        // 8 x 128B contiguous aligned segments -> no partial-line RMW
#pragma unroll
        for (int i = lane * 4; i < NCH * PIECE; i += 64 * 4) {
            int c = i >> 5;                  // / PIECE
            int j = i & (PIECE - 1);
            int g = spanBase + c * L_CHUNK + p * PIECE + j;
            if (g < spanEnd) {
                float4 v4 = make_float4(ost[c*PITCH + j],
                                        ost[c*PITCH + j + 1],
                                        ost[c*PITCH + j + 2],
                                        ost[c*PITCH + j + 3]);
                *(float4*)(yr + g) = v4;
            }
        }
    }
}

// ---- host-side coefficient computation (double, matching numpy refs) ----

static BQ norm_ba(double b0, double b1, double b2,
                  double a0, double a1, double a2) {
    BQ r;
    r.b0 = (float)(b0/a0); r.b1 = (float)(b1/a0); r.b2 = (float)(b2/a0);
    r.a1 = (float)(a1/a0); r.a2 = (float)(a2/a0);
    return r;
}

static BQ make_eq(double f0, double gain_db, double Q) {
    const double SR = 44100.0;
    double w0 = 2.0 * M_PI * f0 / SR;
    double alpha = sin(w0) / (2.0 * Q);
    double A = pow(10.0, gain_db / 40.0);
    return norm_ba(1.0 + alpha*A, -2.0*cos(w0), 1.0 - alpha*A,
                   1.0 + alpha/A, -2.0*cos(w0), 1.0 - alpha/A);
}

static BQ make_lp(double cutoff, double Q) {
    const double SR = 44100.0;
    double w0 = 2.0 * M_PI * cutoff / SR;
    double alpha = sin(w0) / (2.0 * Q);
    double c = cos(w0);
    return norm_ba((1.0-c)/2.0, 1.0-c, (1.0-c)/2.0,
                   1.0+alpha, -2.0*c, 1.0-alpha);
}

static BQ make_hp(double cutoff, double Q) {
    const double SR = 44100.0;
    double w0 = 2.0 * M_PI * cutoff / SR;
    double alpha = sin(w0) / (2.0 * Q);
    double c = cos(w0);
    return norm_ba((1.0+c)/2.0, -(1.0+c), (1.0+c)/2.0,
                   1.0+alpha, -2.0*c, 1.0-alpha);
}

extern "C" void kernel_launch(void* const* d_in, const int* in_sizes, int n_in,
                              void* d_out, int out_size, void* d_ws, size_t ws_size,
                              hipStream_t stream) {
    const float* x = (const float*)d_in[0];
    float* out = (float*)d_out;

    const int T = 441000;
    int total = in_sizes[0];
    int B = total / T;                                  // 32

    int chunksPerRow = (T + L_CHUNK - 1) / L_CHUNK;     // 6891
    int wavesPerRow  = (chunksPerRow + NCH - 1) / NCH;  // 108

    BQ f1 = make_eq(1000.0, 6.0, 1.0);
    BQ f2 = make_lp(8000.0, 0.7071067811865476);
    BQ f3 = make_hp(300.0, 0.7071067811865476);

    dim3 grid(wavesPerRow, B);
    hipLaunchKernelGGL(biquad3_kernel, grid, dim3(64), 0, stream,
                       x, out, T, f1, f2, f3);
}

// Round 3
// 140.614 us; speedup vs baseline: 1.2395x; 1.1530x over previous
//
#include <hip/hip_runtime.h>
#include <math.h>

// RandomMicEQ: cascade of 3 biquads (EQ -> LP -> HP), stage outputs clamped
// to [-1,1], recursion history UNCLAMPED (matches jax ref).
//
// R6: exact intra-block state scan (eliminates warm-up redundancy).
// R5 counters: FETCH fixed (29MB) but dur flat at 93us -- 0.95 waves/SIMD
// resident, VALU 38%: latency-exposed serial loop, 4x warm-up redundancy.
// Each biquad stage is LINEAR in its recursion (clamps only between stages),
// so: every lane runs its 64-sample chunk from ZERO state (local pass),
// a 6-step Kogge-Stone scan over 2-dim states (A^64 and squarings,
// host-precomputed in double) reconstructs each chunk's true init state
// EXACTLY; true output = local + c1(t)*init.y1 + c2(t)*init.y2 with
// c(t) = first row of A^(t+1) (host table). Clamp applied at consumption.
// Block = 64 chunks; only 3 are block-boundary warm-up (W=192 as before;
// block 0 exact). Serial work/wave: 256*21 -> ~3*64*11 ops. LDS 18.5KB
// (in-place passes, pitch-65 = 2-way bank-free) -> 2 waves/SIMD resident.

struct BQ { float b0, b1, b2, a1, a2; };

#define L_CHUNK 64
#define NWARM   3
#define NCH     64                     // chunks per block (= lanes)
#define NOUT    (NCH - NWARM)          // 61 output chunks
#define SPAN    (NCH * L_CHUNK)        // 4096 dwords input span
#define SPAN_P  (SPAN + SPAN / 64)     // 4160 padded (+1 dword per 64)
#define OUTSPAN (NOUT * L_CHUNK)       // 3904
#define WOFF    (NWARM * L_CHUNK)      // 192
// per-stage host table: c1[64] c2[64] scanM[6][4]  = 152 floats
#define TAB_STRIDE 152
#define TAB_TOTAL  (3 * TAB_STRIDE)    // 456

__device__ __forceinline__ float clamp1(float v) {
    return fminf(fmaxf(v, -1.f), 1.f);
}

__global__ __launch_bounds__(64) void biquad3_kernel(
    const float* __restrict__ x, float* __restrict__ out,
    const float* __restrict__ tab, int T, BQ F1, BQ F2, BQ F3)
{
    __shared__ float buf[SPAN_P];      // in-place: x -> y1loc -> y2loc -> y3
    __shared__ float tl[TAB_TOTAL];    // c-tables + scan matrices

    const int lane = threadIdx.x;
    const int row  = blockIdx.y;
    const int col0 = blockIdx.x * OUTSPAN;   // first output column
    const int base = col0 - WOFF;            // input span start (may be <0)

    const float* xr = x   + (size_t)row * T;
    float*       yr = out + (size_t)row * T;

    // ---- load tables (broadcast data, tiny) ----
    for (int i = lane; i < TAB_TOTAL; i += 64) tl[i] = tab[i];

    // ---- stage unique input span, coalesced; zeros outside [0,T) ----
    for (int m = lane * 4; m < SPAN; m += 256) {
        int g = base + m;
        float4 v;
        if (g >= 0 && g + 4 <= T) {
            v = *(const float4*)(xr + g);
        } else {
            v.x = ((unsigned)(g+0) < (unsigned)T) ? xr[g+0] : 0.f;
            v.y = ((unsigned)(g+1) < (unsigned)T) ? xr[g+1] : 0.f;
            v.z = ((unsigned)(g+2) < (unsigned)T) ? xr[g+2] : 0.f;
            v.w = ((unsigned)(g+3) < (unsigned)T) ? xr[g+3] : 0.f;
        }
        int pm = m + (m >> 6);
        buf[pm+0] = v.x; buf[pm+1] = v.y; buf[pm+2] = v.z; buf[pm+3] = v.w;
    }
    __syncthreads();

    const int pmb = lane * (L_CHUNK + 1);   // lane's contiguous 65-dword slot

    // one stage pass: read prev-stage loc (or raw x) from buf, apply
    // correction+clamp (if corr), run FIR+IIR from zero state, write this
    // stage's UNCLAMPED local y back in place; then scan the chunk-final
    // states to get true init states for the NEXT pass's correction.
    float s1x, s1y, s2x, s2y, s3x, s3y;     // inclusive scan results

    auto pass = [&](const BQ& F, const float* pc, const float* mats,
                    bool corr, float iinx, float iiny, float ipvx, float ipvy,
                    float& sx, float& sy) {
        // prehistory: last 2 inputs from lane-1's chunk tail (t=63,62)
        float h1 = 0.f, h2 = 0.f;
        if (lane > 0) {
            float a = buf[pmb - 2];          // lane-1, t=63
            float b = buf[pmb - 3];          // lane-1, t=62
            if (corr) {
                a = clamp1(a + pc[63] * ipvx + pc[64+63] * ipvy);
                b = clamp1(b + pc[62] * ipvx + pc[64+62] * ipvy);
            } else { a = a; b = b; }
            h1 = a; h2 = b;
        }
        __syncthreads();                     // prehistory reads before overwrites
        float x1 = h1, x2 = h2, y1 = 0.f, y2 = 0.f;
#pragma unroll 4
        for (int t = 0; t < L_CHUNK; ++t) {
            float v = buf[pmb + t];
            if (corr) v = clamp1(v + pc[t] * iinx + pc[64+t] * iiny);
            float f = F.b0*v + F.b1*x1 + F.b2*x2;
            float y = (f - F.a2*y2) - F.a1*y1;
            x2 = x1; x1 = v; y2 = y1; y1 = y;
            buf[pmb + t] = y;                // unclamped local y
        }
        // Kogge-Stone scan: s_i = A64*s_{i-1} + loc_i over 64 lanes
        float sx_ = y1, sy_ = y2;            // loc = (y[63], y[62])
#pragma unroll
        for (int k = 0; k < 6; ++k) {
            int d = 1 << k;
            float M00 = mats[4*k+0], M01 = mats[4*k+1];
            float M10 = mats[4*k+2], M11 = mats[4*k+3];
            float px = __shfl_up(sx_, d, 64);
            float py = __shfl_up(sy_, d, 64);
            if (lane >= d) {
                sx_ += M00*px + M01*py;
                sy_ += M10*px + M11*py;
            }
        }
        __syncthreads();                     // loop writes visible to next pass
        sx = sx_; sy = sy_;
    };

    // ---- pass 1: stage 1 on raw input (no correction) ----
    pass(F1, nullptr, tl + 128, false, 0.f, 0.f, 0.f, 0.f, s1x, s1y);
    float i1x = __shfl_up(s1x, 1, 64), i1y = __shfl_up(s1y, 1, 64);
    if (lane == 0) { i1x = 0.f; i1y = 0.f; }
    float p1x = __shfl_up(s1x, 2, 64), p1y = __shfl_up(s1y, 2, 64);
    if (lane <= 1) { p1x = 0.f; p1y = 0.f; }

    // ---- pass 2: stage 2 on corrected+clamped stage-1 output ----
    pass(F2, tl + 0, tl + TAB_STRIDE + 128, true, i1x, i1y, p1x, p1y, s2x, s2y);
    float i2x = __shfl_up(s2x, 1, 64), i2y = __shfl_up(s2y, 1, 64);
    if (lane == 0) { i2x = 0.f; i2y = 0.f; }
    float p2x = __shfl_up(s2x, 2, 64), p2y = __shfl_up(s2y, 2, 64);
    if (lane <= 1) { p2x = 0.f; p2y = 0.f; }

    // ---- pass 3: stage 3 on corrected+clamped stage-2 output ----
    pass(F3, tl + TAB_STRIDE, tl + 2*TAB_STRIDE + 128, true,
         i2x, i2y, p2x, p2y, s3x, s3y);
    float i3x = __shfl_up(s3x, 1, 64), i3y = __shfl_up(s3y, 1, 64);
    if (lane == 0) { i3x = 0.f; i3y = 0.f; }

    // ---- write-back: correct + clamp stage-3 output in place ----
    const float* pc3 = tl + 2*TAB_STRIDE;
#pragma unroll 4
    for (int t = 0; t < L_CHUNK; ++t) {
        float v = buf[pmb + t] + pc3[t] * i3x + pc3[64+t] * i3y;
        buf[pmb + t] = clamp1(v);
    }
    __syncthreads();

    // ---- coalesced flush of the 61 output chunks ----
    for (int mm = lane * 4; mm < OUTSPAN; mm += 256) {
        int m  = WOFF + mm;
        int pm = m + (m >> 6);
        int g  = col0 + mm;
        if (g < T) {
            float4 v4 = make_float4(buf[pm+0], buf[pm+1], buf[pm+2], buf[pm+3]);
            *(float4*)(yr + g) = v4;
        }
    }
}

// ---- host side ----------------------------------------------------------

static void norm_ba(double b0, double b1, double b2,
                    double a0, double a1, double a2, BQ* r,
                    double* oa1, double* oa2) {
    r->b0 = (float)(b0/a0); r->b1 = (float)(b1/a0); r->b2 = (float)(b2/a0);
    r->a1 = (float)(a1/a0); r->a2 = (float)(a2/a0);
    // use float-rounded coeffs (what the kernel iterates) for the tables
    *oa1 = (double)r->a1; *oa2 = (double)r->a2;
}

static void make_eq(double f0, double gain_db, double Q, BQ* r, double* a1, double* a2) {
    const double SR = 44100.0;
    double w0 = 2.0 * M_PI * f0 / SR;
    double alpha = sin(w0) / (2.0 * Q);
    double A = pow(10.0, gain_db / 40.0);
    norm_ba(1.0 + alpha*A, -2.0*cos(w0), 1.0 - alpha*A,
            1.0 + alpha/A, -2.0*cos(w0), 1.0 - alpha/A, r, a1, a2);
}

static void make_lp(double cutoff, double Q, BQ* r, double* a1, double* a2) {
    const double SR = 44100.0;
    double w0 = 2.0 * M_PI * cutoff / SR;
    double alpha = sin(w0) / (2.0 * Q);
    double c = cos(w0);
    norm_ba((1.0-c)/2.0, 1.0-c, (1.0-c)/2.0,
            1.0+alpha, -2.0*c, 1.0-alpha, r, a1, a2);
}

static void make_hp(double cutoff, double Q, BQ* r, double* a1, double* a2) {
    const double SR = 44100.0;
    double w0 = 2.0 * M_PI * cutoff / SR;
    double alpha = sin(w0) / (2.0 * Q);
    double c = cos(w0);
    norm_ba((1.0+c)/2.0, -(1.0+c), (1.0+c)/2.0,
            1.0+alpha, -2.0*c, 1.0-alpha, r, a1, a2);
}

// per-stage table: c1[64]=A^(t+1)[0][0], c2[64]=A^(t+1)[0][1],
// scan matrices A^64, A^128, ..., A^2048 (4 floats each), all double-math.
static void fill_stage_tab(double a1, double a2, float* d) {
    double C00 = -a1, C01 = -a2, C10 = 1.0, C11 = 0.0;   // A^1
    double A64[4] = {0,0,0,0};
    for (int t = 0; t < 64; ++t) {
        d[t]      = (float)C00;
        d[64 + t] = (float)C01;
        if (t == 63) { A64[0]=C00; A64[1]=C01; A64[2]=C10; A64[3]=C11; }
        double n00 = -a1*C00 - a2*C10, n01 = -a1*C01 - a2*C11;
        double n10 =  C00,             n11 =  C01;
        C00 = n00; C01 = n01; C10 = n10; C11 = n11;
    }
    double M00 = A64[0], M01 = A64[1], M10 = A64[2], M11 = A64[3];
    for (int k = 0; k < 6; ++k) {
        d[128 + 4*k + 0] = (float)M00; d[128 + 4*k + 1] = (float)M01;
        d[128 + 4*k + 2] = (float)M10; d[128 + 4*k + 3] = (float)M11;
        double n00 = M00*M00 + M01*M10, n01 = M00*M01 + M01*M11;
        double n10 = M10*M00 + M11*M10, n11 = M10*M01 + M11*M11;
        M00 = n00; M01 = n01; M10 = n10; M11 = n11;
    }
}

extern "C" void kernel_launch(void* const* d_in, const int* in_sizes, int n_in,
                              void* d_out, int out_size, void* d_ws, size_t ws_size,
                              hipStream_t stream) {
    const float* x = (const float*)d_in[0];
    float* out = (float*)d_out;

    const int T = 441000;
    int total = in_sizes[0];
    int B = total / T;                                  // 32

    BQ f1, f2, f3; double a1, a2;
    static float host_tab[TAB_TOTAL];
    make_eq(1000.0, 6.0, 1.0, &f1, &a1, &a2);
    fill_stage_tab(a1, a2, host_tab + 0);
    make_lp(8000.0, 0.7071067811865476, &f2, &a1, &a2);
    fill_stage_tab(a1, a2, host_tab + TAB_STRIDE);
    make_hp(300.0, 0.7071067811865476, &f3, &a1, &a2);
    fill_stage_tab(a1, a2, host_tab + 2*TAB_STRIDE);

    hipMemcpyAsync(d_ws, host_tab, sizeof(host_tab),
                   hipMemcpyHostToDevice, stream);

    int blocksPerRow = (T + OUTSPAN - 1) / OUTSPAN;     // 113
    dim3 grid(blocksPerRow, B);
    hipLaunchKernelGGL(biquad3_kernel, grid, dim3(64), 0, stream,
                       x, out, (const float*)d_ws, T, f1, f2, f3);
}

// Round 4
// 114.795 us; speedup vs baseline: 1.5183x; 1.2249x over previous
//
#include <hip/hip_runtime.h>
#include <math.h>

// RandomMicEQ: cascade of 3 biquads (EQ -> LP -> HP), stage outputs clamped
// to [-1,1], recursion history UNCLAMPED (matches jax ref).
//
// R7: register-resident passes. R6 counters: dur 62us, VALU 22.6%, Occ 16%
// -- latency-bound on ~8 LDS ops/sample (in-place passes + table reads) with
// only ~2 waves/SIMD resident (18.9KB LDS cap). Fix: lane's 64-sample chunk
// lives in float d[64] (VGPRs); all 3 stage passes are pure register+shfl.
//  - correction c1(t)*iy1+c2(t)*iy2 == homogeneous recursion
//    h_t = -a1*h_{t-1} - a2*h_{t-2} seeded by scanned init state: 2 FMA,
//    no table, no LDS. Tables/d_ws deleted; scan matrices are kernel args.
//  - prehistory (x_{-1},x_{-2}) per stage via __shfl_up of corrected
//    d[63],d[62] from lane-1 (zero for lane 0).
//  - LDS = one 8.3KB buffer used only for the two transposes (in: 2 halves
//    coalesced->chunked, pitch 65 = conflict-free; out: reverse).
// LDS 8.3KB + VGPR ~100 with __launch_bounds__(64,4): 4 waves/SIMD resident
// (grid = 14.1 blocks/CU, nearly fully co-resident).
// Exactness: scan is exact within block; block boundary = zero state 192
// samples early (3 warm chunks discarded), as R3-R6. Block 0 exact.

struct BQ { float b0, b1, b2, a1, a2; };
struct ScanM { float m[6][4]; };       // A64^(2^k), k=0..5, row-major 2x2

#define L_CHUNK 64
#define NWARM   3
#define NCH     64                     // chunks per block (= lanes)
#define NOUT    (NCH - NWARM)          // 61
#define SPAN    (NCH * L_CHUNK)        // 4096
#define HALF    (SPAN / 2)             // 2048
#define OUTSPAN (NOUT * L_CHUNK)       // 3904
#define WOFF    (NWARM * L_CHUNK)      // 192
#define BUF_P   (HALF + HALF / 64)     // 2080 dwords = 8320 B

__device__ __forceinline__ float clamp1(float v) {
    return fminf(fmaxf(v, -1.f), 1.f);
}

__global__ __launch_bounds__(64, 4) void biquad3_kernel(
    const float* __restrict__ x, float* __restrict__ out, int T,
    BQ F1, BQ F2, BQ F3, ScanM S1, ScanM S2, ScanM S3)
{
    __shared__ float buf[BUF_P];

    const int lane = threadIdx.x;
    const int row  = blockIdx.y;
    const int col0 = blockIdx.x * OUTSPAN;
    const int base = col0 - WOFF;            // may be < 0 (zero-padded)

    const float* xr = x   + (size_t)row * T;
    float*       yr = out + (size_t)row * T;

    float d[64];                             // lane's chunk, register-resident

    // stage half [h0, h0+HALF) of the span into buf, coalesced, zero-padded
    auto stage_half = [&](int h0) {
#pragma unroll
        for (int m = lane * 4; m < HALF; m += 256) {
            int g = base + h0 + m;
            float4 v;
            if (g >= 0 && g + 4 <= T) {
                v = *(const float4*)(xr + g);
            } else {
                v.x = ((unsigned)(g+0) < (unsigned)T) ? xr[g+0] : 0.f;
                v.y = ((unsigned)(g+1) < (unsigned)T) ? xr[g+1] : 0.f;
                v.z = ((unsigned)(g+2) < (unsigned)T) ? xr[g+2] : 0.f;
                v.w = ((unsigned)(g+3) < (unsigned)T) ? xr[g+3] : 0.f;
            }
            int pm = m + (m >> 6);           // +1 dword per 64: pitch 65
            buf[pm+0] = v.x; buf[pm+1] = v.y; buf[pm+2] = v.z; buf[pm+3] = v.w;
        }
    };

    // ---- input transpose: two halves; 32 lanes pick up chunks per half ----
    stage_half(0);
    __syncthreads();
    if (lane < 32) {
        const int b0i = lane * 65;           // stride 65 across lanes: no conflict
#pragma unroll
        for (int t = 0; t < 64; ++t) d[t] = buf[b0i + t];
    }
    __syncthreads();                         // WAR before overwriting buf
    stage_half(HALF);
    __syncthreads();
    if (lane >= 32) {
        const int b0i = (lane - 32) * 65;
#pragma unroll
        for (int t = 0; t < 64; ++t) d[t] = buf[b0i + t];
    }
    __syncthreads();                         // before out-phase reuses buf

    // ---- one stage: local zero-state pass, state scan, correct+clamp ----
    auto run_stage = [&](const BQ& F, const ScanM& S) {
        // prehistory: lane-1's (corrected) last two inputs
        float ph1 = __shfl_up(d[63], 1, 64);
        float ph2 = __shfl_up(d[62], 1, 64);
        if (lane == 0) { ph1 = 0.f; ph2 = 0.f; }
        // local pass from zero y-state, overwrite d with UNCLAMPED local y
        float xx1 = ph1, xx2 = ph2, yy1 = 0.f, yy2 = 0.f;
#pragma unroll
        for (int t = 0; t < 64; ++t) {
            float v = d[t];
            float f = F.b0*v + F.b1*xx1 + F.b2*xx2;
            float y = (f - F.a2*yy2) - F.a1*yy1;
            xx2 = xx1; xx1 = v; yy2 = yy1; yy1 = y;
            d[t] = y;
        }
        // Kogge-Stone inclusive scan of s_i = A64 * s_{i-1} + loc_i
        float sx = yy1, sy = yy2;            // loc = (y63, y62)
#pragma unroll
        for (int k = 0; k < 6; ++k) {
            float px = __shfl_up(sx, 1 << k, 64);
            float py = __shfl_up(sy, 1 << k, 64);
            if (lane >= (1 << k)) {
                sx += S.m[k][0]*px + S.m[k][1]*py;
                sy += S.m[k][2]*px + S.m[k][3]*py;
            }
        }
        // exclusive: lane's true init state (y_{-1}, y_{-2})
        float ix = __shfl_up(sx, 1, 64);
        float iy = __shfl_up(sy, 1, 64);
        if (lane == 0) { ix = 0.f; iy = 0.f; }
        // correction = homogeneous response to init state; clamp at output
        float h1 = ix, h2 = iy;
#pragma unroll
        for (int t = 0; t < 64; ++t) {
            float h = -F.a1*h1 - F.a2*h2;
            d[t] = clamp1(d[t] + h);
            h2 = h1; h1 = h;
        }
    };

    run_stage(F1, S1);
    run_stage(F2, S2);
    run_stage(F3, S3);

    // ---- output transpose + coalesced flush, two halves ----
    if (lane < 32) {
        const int b0i = lane * 65;
#pragma unroll
        for (int t = 0; t < 64; ++t) buf[b0i + t] = d[t];
    }
    __syncthreads();
    for (int mm = WOFF + lane * 4; mm < HALF; mm += 256) {
        int pm = mm + (mm >> 6);
        int g  = col0 + mm - WOFF;           // g%4==0, T%4==0
        if (g < T) {
            float4 v4 = make_float4(buf[pm+0], buf[pm+1], buf[pm+2], buf[pm+3]);
            *(float4*)(yr + g) = v4;
        }
    }
    __syncthreads();                         // WAR before half B writes
    if (lane >= 32) {
        const int b0i = (lane - 32) * 65;
#pragma unroll
        for (int t = 0; t < 64; ++t) buf[b0i + t] = d[t];
    }
    __syncthreads();
    for (int mm = HALF + lane * 4; mm < SPAN; mm += 256) {
        int mo = mm - HALF;
        int pm = mo + (mo >> 6);
        int g  = col0 + mm - WOFF;
        if (g < T) {
            float4 v4 = make_float4(buf[pm+0], buf[pm+1], buf[pm+2], buf[pm+3]);
            *(float4*)(yr + g) = v4;
        }
    }
}

// ---- host side ----------------------------------------------------------

static void norm_ba(double b0, double b1, double b2,
                    double a0, double a1, double a2, BQ* r,
                    double* oa1, double* oa2) {
    r->b0 = (float)(b0/a0); r->b1 = (float)(b1/a0); r->b2 = (float)(b2/a0);
    r->a1 = (float)(a1/a0); r->a2 = (float)(a2/a0);
    // tables/matrices built from the float-rounded coeffs the kernel iterates
    *oa1 = (double)r->a1; *oa2 = (double)r->a2;
}

static void make_eq(double f0, double gain_db, double Q, BQ* r, double* a1, double* a2) {
    const double SR = 44100.0;
    double w0 = 2.0 * M_PI * f0 / SR;
    double alpha = sin(w0) / (2.0 * Q);
    double A = pow(10.0, gain_db / 40.0);
    norm_ba(1.0 + alpha*A, -2.0*cos(w0), 1.0 - alpha*A,
            1.0 + alpha/A, -2.0*cos(w0), 1.0 - alpha/A, r, a1, a2);
}

static void make_lp(double cutoff, double Q, BQ* r, double* a1, double* a2) {
    const double SR = 44100.0;
    double w0 = 2.0 * M_PI * cutoff / SR;
    double alpha = sin(w0) / (2.0 * Q);
    double c = cos(w0);
    norm_ba((1.0-c)/2.0, 1.0-c, (1.0-c)/2.0,
            1.0+alpha, -2.0*c, 1.0-alpha, r, a1, a2);
}

static void make_hp(double cutoff, double Q, BQ* r, double* a1, double* a2) {
    const double SR = 44100.0;
    double w0 = 2.0 * M_PI * cutoff / SR;
    double alpha = sin(w0) / (2.0 * Q);
    double c = cos(w0);
    norm_ba((1.0+c)/2.0, -(1.0+c), (1.0+c)/2.0,
            1.0+alpha, -2.0*c, 1.0-alpha, r, a1, a2);
}

// S.m[k] = A64^(2^k) where A = [[-a1,-a2],[1,0]], all double math
static void fill_scan(double a1, double a2, ScanM* S) {
    double M[4] = { -a1, -a2, 1.0, 0.0 };    // A^1
    for (int i = 0; i < 6; ++i) {            // -> A^64
        double n0 = M[0]*M[0] + M[1]*M[2], n1 = M[0]*M[1] + M[1]*M[3];
        double n2 = M[2]*M[0] + M[3]*M[2], n3 = M[2]*M[1] + M[3]*M[3];
        M[0]=n0; M[1]=n1; M[2]=n2; M[3]=n3;
    }
    for (int k = 0; k < 6; ++k) {            // A64^(2^k)
        S->m[k][0] = (float)M[0]; S->m[k][1] = (float)M[1];
        S->m[k][2] = (float)M[2]; S->m[k][3] = (float)M[3];
        double n0 = M[0]*M[0] + M[1]*M[2], n1 = M[0]*M[1] + M[1]*M[3];
        double n2 = M[2]*M[0] + M[3]*M[2], n3 = M[2]*M[1] + M[3]*M[3];
        M[0]=n0; M[1]=n1; M[2]=n2; M[3]=n3;
    }
}

extern "C" void kernel_launch(void* const* d_in, const int* in_sizes, int n_in,
                              void* d_out, int out_size, void* d_ws, size_t ws_size,
                              hipStream_t stream) {
    const float* x = (const float*)d_in[0];
    float* out = (float*)d_out;

    const int T = 441000;
    int total = in_sizes[0];
    int B = total / T;                                  // 32

    BQ f1, f2, f3; double a1, a2;
    ScanM s1, s2, s3;
    make_eq(1000.0, 6.0, 1.0, &f1, &a1, &a2);           fill_scan(a1, a2, &s1);
    make_lp(8000.0, 0.7071067811865476, &f2, &a1, &a2); fill_scan(a1, a2, &s2);
    make_hp(300.0, 0.7071067811865476, &f3, &a1, &a2);  fill_scan(a1, a2, &s3);

    int blocksPerRow = (T + OUTSPAN - 1) / OUTSPAN;     // 113
    dim3 grid(blocksPerRow, B);
    hipLaunchKernelGGL(biquad3_kernel, grid, dim3(64), 0, stream,
                       x, out, T, f1, f2, f3, s1, s2, s3);
}

// Round 5
// 108.148 us; speedup vs baseline: 1.6116x; 1.0615x over previous
//
#include <hip/hip_runtime.h>
#include <math.h>

// RandomMicEQ: cascade of 3 biquads (EQ -> LP -> HP), stage outputs clamped
// to [-1,1], recursion history UNCLAMPED (matches jax ref).
//
// R8: direct-to-register input. R7 (register passes + scan) got kernel to
// ~37us, but input still took an LDS round-trip: stage, sync, 128 exec-
// masked ds_read_b32, 3 barriers -- all serial at block start. Chunks in a
// block are DISJOINT (redundancy only the 3 warm chunks), so each lane now
// loads its own 64 samples directly: 16 independent global_load_dwordx4
// into d[64]. A wave's loads cover one contiguous 16KB span (every line
// fetched once, ~1.05x grid-wide); 16 back-to-back loads expose ~1 miss
// latency, hidden across 16 waves/CU. Input LDS phase deleted; compute
// starts with no block-wide sync. Output transpose keeps the LDS path
// (full-line coalesced stores; R2 showed scattered stores cause RMW
// write amplification).
//
// Algorithm (R6/R7): per stage, lanes run zero-state local pass in
// registers; 6-step Kogge-Stone scan of 2-dim states (A^64 powers, host
// double) reconstructs exact init states; correction = homogeneous
// recursion seeded by init state; clamp at consumption. Block boundary =
// zero state 192 samples early (3 warm chunks discarded). Block 0 exact.

struct BQ { float b0, b1, b2, a1, a2; };
struct ScanM { float m[6][4]; };       // A64^(2^k), k=0..5, row-major 2x2

#define L_CHUNK 64
#define NWARM   3
#define NCH     64                     // chunks per block (= lanes)
#define NOUT    (NCH - NWARM)          // 61
#define SPAN    (NCH * L_CHUNK)        // 4096
#define HALF    (SPAN / 2)             // 2048
#define OUTSPAN (NOUT * L_CHUNK)       // 3904
#define WOFF    (NWARM * L_CHUNK)      // 192
#define BUF_P   (HALF + HALF / 64)     // 2080 dwords = 8320 B

__device__ __forceinline__ float clamp1(float v) {
    return fminf(fmaxf(v, -1.f), 1.f);
}

__global__ __launch_bounds__(64, 4) void biquad3_kernel(
    const float* __restrict__ x, float* __restrict__ out, int T,
    BQ F1, BQ F2, BQ F3, ScanM S1, ScanM S2, ScanM S3)
{
    __shared__ float buf[BUF_P];             // output transpose staging only

    const int lane = threadIdx.x;
    const int row  = blockIdx.y;
    const int col0 = blockIdx.x * OUTSPAN;
    const int base = col0 - WOFF;            // may be < 0 (zero-padded)

    const float* xr = x   + (size_t)row * T;
    float*       yr = out + (size_t)row * T;

    float d[64];                             // lane's chunk, register-resident

    // ---- direct strided load of lane's 64-sample chunk ----
    const int cbase = base + lane * L_CHUNK;
    if (cbase >= 0 && cbase + L_CHUNK <= T) {
#pragma unroll
        for (int j = 0; j < 16; ++j) {
            float4 v = *(const float4*)(xr + cbase + 4*j);
            d[4*j+0] = v.x; d[4*j+1] = v.y; d[4*j+2] = v.z; d[4*j+3] = v.w;
        }
    } else {                                 // boundary lanes only
#pragma unroll
        for (int j = 0; j < 64; ++j) {
            int g = cbase + j;
            d[j] = ((unsigned)g < (unsigned)T) ? xr[g] : 0.f;
        }
    }

    // ---- one stage: local zero-state pass, state scan, correct+clamp ----
    auto run_stage = [&](const BQ& F, const ScanM& S) {
        // prehistory: lane-1's (corrected) last two inputs
        float ph1 = __shfl_up(d[63], 1, 64);
        float ph2 = __shfl_up(d[62], 1, 64);
        if (lane == 0) { ph1 = 0.f; ph2 = 0.f; }
        // local pass from zero y-state, overwrite d with UNCLAMPED local y
        float xx1 = ph1, xx2 = ph2, yy1 = 0.f, yy2 = 0.f;
#pragma unroll
        for (int t = 0; t < 64; ++t) {
            float v = d[t];
            float f = F.b0*v + F.b1*xx1 + F.b2*xx2;
            float y = (f - F.a2*yy2) - F.a1*yy1;
            xx2 = xx1; xx1 = v; yy2 = yy1; yy1 = y;
            d[t] = y;
        }
        // Kogge-Stone inclusive scan of s_i = A64 * s_{i-1} + loc_i
        float sx = yy1, sy = yy2;            // loc = (y63, y62)
#pragma unroll
        for (int k = 0; k < 6; ++k) {
            float px = __shfl_up(sx, 1 << k, 64);
            float py = __shfl_up(sy, 1 << k, 64);
            if (lane >= (1 << k)) {
                sx += S.m[k][0]*px + S.m[k][1]*py;
                sy += S.m[k][2]*px + S.m[k][3]*py;
            }
        }
        // exclusive: lane's true init state (y_{-1}, y_{-2})
        float ix = __shfl_up(sx, 1, 64);
        float iy = __shfl_up(sy, 1, 64);
        if (lane == 0) { ix = 0.f; iy = 0.f; }
        // correction = homogeneous response to init state; clamp at output
        float h1 = ix, h2 = iy;
#pragma unroll
        for (int t = 0; t < 64; ++t) {
            float h = -F.a1*h1 - F.a2*h2;
            d[t] = clamp1(d[t] + h);
            h2 = h1; h1 = h;
        }
    };

    run_stage(F1, S1);
    run_stage(F2, S2);
    run_stage(F3, S3);

    // ---- output transpose + coalesced flush, two halves ----
    if (lane < 32) {
        const int b0i = lane * 65;           // stride 65: conflict-free
#pragma unroll
        for (int t = 0; t < 64; ++t) buf[b0i + t] = d[t];
    }
    __syncthreads();
    for (int mm = WOFF + lane * 4; mm < HALF; mm += 256) {
        int pm = mm + (mm >> 6);
        int g  = col0 + mm - WOFF;           // g%4==0, T%4==0
        if (g < T) {
            float4 v4 = make_float4(buf[pm+0], buf[pm+1], buf[pm+2], buf[pm+3]);
            *(float4*)(yr + g) = v4;
        }
    }
    __syncthreads();                         // WAR before half B writes
    if (lane >= 32) {
        const int b0i = (lane - 32) * 65;
#pragma unroll
        for (int t = 0; t < 64; ++t) buf[b0i + t] = d[t];
    }
    __syncthreads();
    for (int mm = HALF + lane * 4; mm < SPAN; mm += 256) {
        int mo = mm - HALF;
        int pm = mo + (mo >> 6);
        int g  = col0 + mm - WOFF;
        if (g < T) {
            float4 v4 = make_float4(buf[pm+0], buf[pm+1], buf[pm+2], buf[pm+3]);
            *(float4*)(yr + g) = v4;
        }
    }
}

// ---- host side ----------------------------------------------------------

static void norm_ba(double b0, double b1, double b2,
                    double a0, double a1, double a2, BQ* r,
                    double* oa1, double* oa2) {
    r->b0 = (float)(b0/a0); r->b1 = (float)(b1/a0); r->b2 = (float)(b2/a0);
    r->a1 = (float)(a1/a0); r->a2 = (float)(a2/a0);
    // scan matrices built from the float-rounded coeffs the kernel iterates
    *oa1 = (double)r->a1; *oa2 = (double)r->a2;
}

static void make_eq(double f0, double gain_db, double Q, BQ* r, double* a1, double* a2) {
    const double SR = 44100.0;
    double w0 = 2.0 * M_PI * f0 / SR;
    double alpha = sin(w0) / (2.0 * Q);
    double A = pow(10.0, gain_db / 40.0);
    norm_ba(1.0 + alpha*A, -2.0*cos(w0), 1.0 - alpha*A,
            1.0 + alpha/A, -2.0*cos(w0), 1.0 - alpha/A, r, a1, a2);
}

static void make_lp(double cutoff, double Q, BQ* r, double* a1, double* a2) {
    const double SR = 44100.0;
    double w0 = 2.0 * M_PI * cutoff / SR;
    double alpha = sin(w0) / (2.0 * Q);
    double c = cos(w0);
    norm_ba((1.0-c)/2.0, 1.0-c, (1.0-c)/2.0,
            1.0+alpha, -2.0*c, 1.0-alpha, r, a1, a2);
}

static void make_hp(double cutoff, double Q, BQ* r, double* a1, double* a2) {
    const double SR = 44100.0;
    double w0 = 2.0 * M_PI * cutoff / SR;
    double alpha = sin(w0) / (2.0 * Q);
    double c = cos(w0);
    norm_ba((1.0+c)/2.0, -(1.0+c), (1.0+c)/2.0,
            1.0+alpha, -2.0*c, 1.0-alpha, r, a1, a2);
}

// S.m[k] = A64^(2^k) where A = [[-a1,-a2],[1,0]], all double math
static void fill_scan(double a1, double a2, ScanM* S) {
    double M[4] = { -a1, -a2, 1.0, 0.0 };    // A^1
    for (int i = 0; i < 6; ++i) {            // -> A^64
        double n0 = M[0]*M[0] + M[1]*M[2], n1 = M[0]*M[1] + M[1]*M[3];
        double n2 = M[2]*M[0] + M[3]*M[2], n3 = M[2]*M[1] + M[3]*M[3];
        M[0]=n0; M[1]=n1; M[2]=n2; M[3]=n3;
    }
    for (int k = 0; k < 6; ++k) {            // A64^(2^k)
        S->m[k][0] = (float)M[0]; S->m[k][1] = (float)M[1];
        S->m[k][2] = (float)M[2]; S->m[k][3] = (float)M[3];
        double n0 = M[0]*M[0] + M[1]*M[2], n1 = M[0]*M[1] + M[1]*M[3];
        double n2 = M[2]*M[0] + M[3]*M[2], n3 = M[2]*M[1] + M[3]*M[3];
        M[0]=n0; M[1]=n1; M[2]=n2; M[3]=n3;
    }
}

extern "C" void kernel_launch(void* const* d_in, const int* in_sizes, int n_in,
                              void* d_out, int out_size, void* d_ws, size_t ws_size,
                              hipStream_t stream) {
    const float* x = (const float*)d_in[0];
    float* out = (float*)d_out;

    const int T = 441000;
    int total = in_sizes[0];
    int B = total / T;                                  // 32

    BQ f1, f2, f3; double a1, a2;
    ScanM s1, s2, s3;
    make_eq(1000.0, 6.0, 1.0, &f1, &a1, &a2);           fill_scan(a1, a2, &s1);
    make_lp(8000.0, 0.7071067811865476, &f2, &a1, &a2); fill_scan(a1, a2, &s2);
    make_hp(300.0, 0.7071067811865476, &f3, &a1, &a2);  fill_scan(a1, a2, &s3);

    int blocksPerRow = (T + OUTSPAN - 1) / OUTSPAN;     // 113
    dim3 grid(blocksPerRow, B);
    hipLaunchKernelGGL(biquad3_kernel, grid, dim3(64), 0, stream,
                       x, out, T, f1, f2, f3, s1, s2, s3);
}